// Round 1
// baseline (289.018 us; speedup 1.0000x reference)
//
#include <hip/hip_runtime.h>

#define B_   4
#define H_   8
#define M_   2048
#define D_   512
#define DH_  64

typedef short  bf16x8 __attribute__((ext_vector_type(8)));
typedef float  f32x4  __attribute__((ext_vector_type(4)));

static __device__ __forceinline__ unsigned short f2bf(float f) {
  unsigned u = __float_as_uint(f);
  u += 0x7fffu + ((u >> 16) & 1u);
  return (unsigned short)(u >> 16);
}

static __device__ __forceinline__ int swz128(int row, int byteoff) {
  return row * 128 + (byteoff ^ ((row & 7) << 4));
}

// ---------------- LayerNorm -> bf16 ----------------
__global__ __launch_bounds__(256) void ln_kernel(
    const float* __restrict__ x, const float* __restrict__ gamma,
    const float* __restrict__ beta, unsigned short* __restrict__ xn)
{
  int row = blockIdx.x;
  int t = threadIdx.x;
  const float* xr = x + (size_t)row * D_;
  float v0 = xr[t], v1 = xr[t + 256];
  float s = v0 + v1, ss = v0 * v0 + v1 * v1;
  #pragma unroll
  for (int m = 1; m < 64; m <<= 1) {
    s  += __shfl_xor(s, m);
    ss += __shfl_xor(ss, m);
  }
  __shared__ float red[8];
  int wid = t >> 6;
  if ((t & 63) == 0) { red[wid] = s; red[wid + 4] = ss; }
  __syncthreads();
  s  = red[0] + red[1] + red[2] + red[3];
  ss = red[4] + red[5] + red[6] + red[7];
  float mu  = s * (1.0f / D_);
  float var = ss * (1.0f / D_) - mu * mu;
  float rstd = rsqrtf(var + 1e-5f);
  unsigned short* o = xn + (size_t)row * D_;
  o[t]       = f2bf((v0 - mu) * rstd * gamma[t]       + beta[t]);
  o[t + 256] = f2bf((v1 - mu) * rstd * gamma[t + 256] + beta[t + 256]);
}

// ---------------- weight casts ----------------
__global__ __launch_bounds__(256) void cast_w_kernel(
    const float* __restrict__ wq, const float* __restrict__ wk,
    const float* __restrict__ wv, const float* __restrict__ wo,
    unsigned short* __restrict__ wqkv, unsigned short* __restrict__ wob)
{
  int i = blockIdx.x * 256 + threadIdx.x;   // 262144 total
  wqkv[i]          = f2bf(wq[i]);
  wqkv[i + 262144] = f2bf(wk[i]);
  wqkv[i + 524288] = f2bf(wv[i]);
  wob[i]           = f2bf(wo[i]);
}

// ---------------- QKV GEMM: [8192,512] x [1536,512]^T ----------------
__global__ __launch_bounds__(256) void qkv_gemm(
    const unsigned short* __restrict__ xn,
    const unsigned short* __restrict__ wqkv,
    const float* __restrict__ bq, const float* __restrict__ bk,
    const float* __restrict__ bv,
    unsigned short* __restrict__ q, unsigned short* __restrict__ k,
    unsigned short* __restrict__ vT)
{
  __shared__ __align__(16) char As[128 * 128];
  __shared__ __align__(16) char Bs[128 * 128];
  const int m0 = blockIdx.x * 128;
  const int n0 = blockIdx.y * 128;
  const int t = threadIdx.x, wid = t >> 6, lane = t & 63;
  const int wr = (wid >> 1) * 64, wc = (wid & 1) * 64;
  const int cl = lane & 15, rg = lane >> 4;
  const f32x4 z4 = {0.f, 0.f, 0.f, 0.f};

  f32x4 acc[4][4];
  #pragma unroll
  for (int i = 0; i < 4; ++i)
    #pragma unroll
    for (int j = 0; j < 4; ++j) acc[i][j] = z4;

  for (int k0 = 0; k0 < 512; k0 += 64) {
    __syncthreads();
    #pragma unroll
    for (int i = 0; i < 4; ++i) {
      int c = t + 256 * i;
      int row = c >> 3, off = (c & 7) * 16;
      *(uint4*)(As + swz128(row, off)) =
          *(const uint4*)((const char*)(xn + (size_t)(m0 + row) * 512 + k0) + off);
      *(uint4*)(Bs + swz128(row, off)) =
          *(const uint4*)((const char*)(wqkv + (size_t)(n0 + row) * 512 + k0) + off);
    }
    __syncthreads();
    #pragma unroll
    for (int ks = 0; ks < 2; ++ks) {
      int koff = ks * 64 + rg * 16;
      bf16x8 af[4], bfr[4];
      #pragma unroll
      for (int i = 0; i < 4; ++i)
        af[i] = *(const bf16x8*)(As + swz128(wr + i * 16 + cl, koff));
      #pragma unroll
      for (int j = 0; j < 4; ++j)
        bfr[j] = *(const bf16x8*)(Bs + swz128(wc + j * 16 + cl, koff));
      #pragma unroll
      for (int i = 0; i < 4; ++i)
        #pragma unroll
        for (int j = 0; j < 4; ++j)
          acc[i][j] = __builtin_amdgcn_mfma_f32_16x16x32_bf16(af[i], bfr[j], acc[i][j], 0, 0, 0);
    }
  }

  #pragma unroll
  for (int j = 0; j < 4; ++j) {
    int n = n0 + wc + j * 16 + cl;
    int mat = n >> 9, nn = n & 511;
    int h = nn >> 6, dh = nn & 63;
    float bias = (mat == 0) ? bq[nn] : ((mat == 1) ? bk[nn] : bv[nn]);
    #pragma unroll
    for (int i = 0; i < 4; ++i) {
      #pragma unroll
      for (int r = 0; r < 4; ++r) {
        int mrow = m0 + wr + i * 16 + rg * 4 + r;
        int b = mrow >> 11, mm = mrow & 2047;
        unsigned short val = f2bf(acc[i][j][r] + bias);
        size_t bh = (size_t)(b * H_ + h);
        if (mat == 0)      q [(bh * M_ + mm) * DH_ + dh] = val;
        else if (mat == 1) k [(bh * M_ + mm) * DH_ + dh] = val;
        else               vT[(bh * DH_ + dh) * M_ + mm] = val;
      }
    }
  }
}

// ---------------- Attention: S=QK^T/8, mask diag, softmax, attn out, PV ----------------
__global__ __launch_bounds__(256) void attn_kernel(
    const unsigned short* __restrict__ q,
    const unsigned short* __restrict__ k,
    const unsigned short* __restrict__ vT,
    float* __restrict__ attn,
    unsigned short* __restrict__ ctx)
{
  __shared__ __align__(16) char Qs[128 * 128];
  __shared__ __align__(16) char Ks[64 * 128];
  __shared__ __align__(16) char Vs[64 * 128];
  __shared__ __align__(16) char Ps[128 * 128];

  const int bh = blockIdx.y;
  const int m0 = blockIdx.x * 128;
  const int t = threadIdx.x, wid = t >> 6, lane = t & 63;
  const int wr = wid * 32;
  const int cl = lane & 15, rg = lane >> 4;
  const f32x4 z4 = {0.f, 0.f, 0.f, 0.f};

  const unsigned short* qb = q  + (size_t)bh * M_ * DH_;
  const unsigned short* kb = k  + (size_t)bh * M_ * DH_;
  const unsigned short* vb = vT + (size_t)bh * DH_ * M_;
  float* ab = attn + (size_t)bh * M_ * M_;

  // Q tile: rows m0..m0+127, 64 bf16 each (contiguous 16 KB)
  #pragma unroll
  for (int i = 0; i < 4; ++i) {
    int c = t + 256 * i;
    *(uint4*)(Qs + swz128(c >> 3, (c & 7) * 16)) =
        *(const uint4*)((const char*)(qb + (size_t)m0 * DH_) + c * 16);
  }

  float mrow[2][4], lrow[2][4];
  #pragma unroll
  for (int i = 0; i < 2; ++i)
    #pragma unroll
    for (int r = 0; r < 4; ++r) { mrow[i][r] = -1e30f; lrow[i][r] = 0.f; }

  // ---- pass 1: running row max / sum ----
  for (int kt = 0; kt < 32; ++kt) {
    __syncthreads();
    #pragma unroll
    for (int i = 0; i < 2; ++i) {
      int c = t + 256 * i;
      *(uint4*)(Ks + swz128(c >> 3, (c & 7) * 16)) =
          *(const uint4*)((const char*)(kb + (size_t)kt * 64 * DH_) + c * 16);
    }
    __syncthreads();
    f32x4 s[2][4];
    #pragma unroll
    for (int i = 0; i < 2; ++i)
      #pragma unroll
      for (int j = 0; j < 4; ++j) s[i][j] = z4;
    #pragma unroll
    for (int ks = 0; ks < 2; ++ks) {
      int koff = ks * 64 + rg * 16;
      bf16x8 aq[2], bk8[4];
      #pragma unroll
      for (int i = 0; i < 2; ++i)
        aq[i] = *(const bf16x8*)(Qs + swz128(wr + i * 16 + cl, koff));
      #pragma unroll
      for (int j = 0; j < 4; ++j)
        bk8[j] = *(const bf16x8*)(Ks + swz128(j * 16 + cl, koff));
      #pragma unroll
      for (int i = 0; i < 2; ++i)
        #pragma unroll
        for (int j = 0; j < 4; ++j)
          s[i][j] = __builtin_amdgcn_mfma_f32_16x16x32_bf16(aq[i], bk8[j], s[i][j], 0, 0, 0);
    }
    #pragma unroll
    for (int i = 0; i < 2; ++i) {
      #pragma unroll
      for (int r = 0; r < 4; ++r) {
        int mg = m0 + wr + i * 16 + rg * 4 + r;
        float sv[4], pm = -1e30f;
        #pragma unroll
        for (int j = 0; j < 4; ++j) {
          int ng = kt * 64 + j * 16 + cl;
          float xx = s[i][j][r] * 0.125f;
          if (ng == mg) xx = -1e30f;
          sv[j] = xx;
          pm = fmaxf(pm, xx);
        }
        #pragma unroll
        for (int msk = 8; msk >= 1; msk >>= 1) pm = fmaxf(pm, __shfl_xor(pm, msk));
        float nm = fmaxf(mrow[i][r], pm);
        float ps = 0.f;
        #pragma unroll
        for (int j = 0; j < 4; ++j) ps += __expf(sv[j] - nm);
        #pragma unroll
        for (int msk = 8; msk >= 1; msk >>= 1) ps += __shfl_xor(ps, msk);
        lrow[i][r] = lrow[i][r] * __expf(mrow[i][r] - nm) + ps;
        mrow[i][r] = nm;
      }
    }
  }

  float rinv[2][4];
  #pragma unroll
  for (int i = 0; i < 2; ++i)
    #pragma unroll
    for (int r = 0; r < 4; ++r) rinv[i][r] = 1.0f / lrow[i][r];

  f32x4 oc[2][4];
  #pragma unroll
  for (int i = 0; i < 2; ++i)
    #pragma unroll
    for (int j = 0; j < 4; ++j) oc[i][j] = z4;

  // ---- pass 2: recompute S, emit attn, PV ----
  for (int kt = 0; kt < 32; ++kt) {
    __syncthreads();
    #pragma unroll
    for (int i = 0; i < 2; ++i) {
      int c = t + 256 * i;
      int row = c >> 3, off = (c & 7) * 16;
      *(uint4*)(Ks + swz128(row, off)) =
          *(const uint4*)((const char*)(kb + (size_t)kt * 64 * DH_) + c * 16);
      *(uint4*)(Vs + swz128(row, off)) =
          *(const uint4*)((const char*)(vb + (size_t)row * M_ + kt * 64) + off);
    }
    __syncthreads();
    f32x4 s[2][4];
    #pragma unroll
    for (int i = 0; i < 2; ++i)
      #pragma unroll
      for (int j = 0; j < 4; ++j) s[i][j] = z4;
    #pragma unroll
    for (int ks = 0; ks < 2; ++ks) {
      int koff = ks * 64 + rg * 16;
      bf16x8 aq[2], bk8[4];
      #pragma unroll
      for (int i = 0; i < 2; ++i)
        aq[i] = *(const bf16x8*)(Qs + swz128(wr + i * 16 + cl, koff));
      #pragma unroll
      for (int j = 0; j < 4; ++j)
        bk8[j] = *(const bf16x8*)(Ks + swz128(j * 16 + cl, koff));
      #pragma unroll
      for (int i = 0; i < 2; ++i)
        #pragma unroll
        for (int j = 0; j < 4; ++j)
          s[i][j] = __builtin_amdgcn_mfma_f32_16x16x32_bf16(aq[i], bk8[j], s[i][j], 0, 0, 0);
    }
    // attn values: write global (fp32, nontemporal) + Ps (bf16, swizzled)
    #pragma unroll
    for (int i = 0; i < 2; ++i) {
      #pragma unroll
      for (int r = 0; r < 4; ++r) {
        int lr = wr + i * 16 + rg * 4 + r;
        int mg = m0 + lr;
        float* arow = ab + (size_t)mg * M_ + kt * 64;
        #pragma unroll
        for (int j = 0; j < 4; ++j) {
          int col = j * 16 + cl;
          int ng = kt * 64 + col;
          float xx = s[i][j][r] * 0.125f;
          float p = (ng == mg) ? 0.f : __expf(xx - mrow[i][r]) * rinv[i][r];
          __builtin_nontemporal_store(p, arow + col);
          *(unsigned short*)(Ps + swz128(lr, col * 2)) = f2bf(p);
        }
      }
    }
    // PV: oc += P(128x64) @ V(64x64)   (wave reads only its own P rows)
    #pragma unroll
    for (int ks = 0; ks < 2; ++ks) {
      int koff = ks * 64 + rg * 16;
      bf16x8 ap[2], bv8[4];
      #pragma unroll
      for (int i = 0; i < 2; ++i)
        ap[i] = *(const bf16x8*)(Ps + swz128(wr + i * 16 + cl, koff));
      #pragma unroll
      for (int j = 0; j < 4; ++j)
        bv8[j] = *(const bf16x8*)(Vs + swz128(j * 16 + cl, koff));
      #pragma unroll
      for (int i = 0; i < 2; ++i)
        #pragma unroll
        for (int j = 0; j < 4; ++j)
          oc[i][j] = __builtin_amdgcn_mfma_f32_16x16x32_bf16(ap[i], bv8[j], oc[i][j], 0, 0, 0);
    }
  }

  // ctx epilogue: [B][M][512] bf16
  int b = bh >> 3, h = bh & 7;
  #pragma unroll
  for (int i = 0; i < 2; ++i) {
    #pragma unroll
    for (int r = 0; r < 4; ++r) {
      int mm = m0 + wr + i * 16 + rg * 4 + r;
      #pragma unroll
      for (int j = 0; j < 4; ++j) {
        int d = j * 16 + cl;
        ctx[((size_t)b * M_ + mm) * D_ + h * DH_ + d] = f2bf(oc[i][j][r]);
      }
    }
  }
}

// ---------------- out = ctx @ wo^T + bo + x ----------------
__global__ __launch_bounds__(256) void out_gemm(
    const unsigned short* __restrict__ ctxb,
    const unsigned short* __restrict__ wob,
    const float* __restrict__ bo,
    const float* __restrict__ x,
    float* __restrict__ out)
{
  __shared__ __align__(16) char As[128 * 128];
  __shared__ __align__(16) char Bs[128 * 128];
  const int m0 = blockIdx.x * 128;
  const int n0 = blockIdx.y * 128;
  const int t = threadIdx.x, wid = t >> 6, lane = t & 63;
  const int wr = (wid >> 1) * 64, wc = (wid & 1) * 64;
  const int cl = lane & 15, rg = lane >> 4;
  const f32x4 z4 = {0.f, 0.f, 0.f, 0.f};

  f32x4 acc[4][4];
  #pragma unroll
  for (int i = 0; i < 4; ++i)
    #pragma unroll
    for (int j = 0; j < 4; ++j) acc[i][j] = z4;

  for (int k0 = 0; k0 < 512; k0 += 64) {
    __syncthreads();
    #pragma unroll
    for (int i = 0; i < 4; ++i) {
      int c = t + 256 * i;
      int row = c >> 3, off = (c & 7) * 16;
      *(uint4*)(As + swz128(row, off)) =
          *(const uint4*)((const char*)(ctxb + (size_t)(m0 + row) * 512 + k0) + off);
      *(uint4*)(Bs + swz128(row, off)) =
          *(const uint4*)((const char*)(wob + (size_t)(n0 + row) * 512 + k0) + off);
    }
    __syncthreads();
    #pragma unroll
    for (int ks = 0; ks < 2; ++ks) {
      int koff = ks * 64 + rg * 16;
      bf16x8 af[4], bfr[4];
      #pragma unroll
      for (int i = 0; i < 4; ++i)
        af[i] = *(const bf16x8*)(As + swz128(wr + i * 16 + cl, koff));
      #pragma unroll
      for (int j = 0; j < 4; ++j)
        bfr[j] = *(const bf16x8*)(Bs + swz128(wc + j * 16 + cl, koff));
      #pragma unroll
      for (int i = 0; i < 4; ++i)
        #pragma unroll
        for (int j = 0; j < 4; ++j)
          acc[i][j] = __builtin_amdgcn_mfma_f32_16x16x32_bf16(af[i], bfr[j], acc[i][j], 0, 0, 0);
    }
  }

  #pragma unroll
  for (int j = 0; j < 4; ++j) {
    int n = n0 + wc + j * 16 + cl;
    float bias = bo[n];
    #pragma unroll
    for (int i = 0; i < 4; ++i) {
      #pragma unroll
      for (int r = 0; r < 4; ++r) {
        int mrow = m0 + wr + i * 16 + rg * 4 + r;
        out[(size_t)mrow * 512 + n] = acc[i][j][r] + bias + x[(size_t)mrow * 512 + n];
      }
    }
  }
}

extern "C" void kernel_launch(void* const* d_in, const int* in_sizes, int n_in,
                              void* d_out, int out_size, void* d_ws, size_t ws_size,
                              hipStream_t stream) {
  const float* x     = (const float*)d_in[0];
  const float* wq    = (const float*)d_in[1];
  const float* bq    = (const float*)d_in[2];
  const float* wk    = (const float*)d_in[3];
  const float* bk    = (const float*)d_in[4];
  const float* wv    = (const float*)d_in[5];
  const float* bv    = (const float*)d_in[6];
  const float* wo    = (const float*)d_in[7];
  const float* bo    = (const float*)d_in[8];
  const float* gamma = (const float*)d_in[9];
  const float* beta  = (const float*)d_in[10];

  char* ws = (char*)d_ws;
  unsigned short* xn   = (unsigned short*)(ws);              //  8,388,608 B
  unsigned short* wqkv = (unsigned short*)(ws + 8388608);    //  1,572,864 B
  unsigned short* wob  = (unsigned short*)(ws + 9961472);    //    524,288 B
  unsigned short* qb   = (unsigned short*)(ws + 10485760);   //  8,388,608 B
  unsigned short* kb   = (unsigned short*)(ws + 18874368);   //  8,388,608 B
  unsigned short* vT   = (unsigned short*)(ws + 27262976);   //  8,388,608 B
  unsigned short* ctx  = (unsigned short*)(ws + 35651584);   //  8,388,608 B

  float* out  = (float*)d_out;
  float* attn = (float*)d_out + 4194304;

  ln_kernel<<<8192, 256, 0, stream>>>(x, gamma, beta, xn);
  cast_w_kernel<<<1024, 256, 0, stream>>>(wq, wk, wv, wo, wqkv, wob);
  qkv_gemm<<<dim3(64, 12), 256, 0, stream>>>(xn, wqkv, bq, bk, bv, qb, kb, vT);
  attn_kernel<<<dim3(16, 32), 256, 0, stream>>>(qb, kb, vT, attn, ctx);
  out_gemm<<<dim3(64, 4), 256, 0, stream>>>(ctx, wob, bo, x, out);
}

// Round 2
// 273.010 us; speedup vs baseline: 1.0586x; 1.0586x over previous
//
#include <hip/hip_runtime.h>

#define B_   4
#define H_   8
#define M_   2048
#define D_   512
#define DH_  64

typedef short  bf16x8 __attribute__((ext_vector_type(8)));
typedef float  f32x4  __attribute__((ext_vector_type(4)));
typedef unsigned short u16x4 __attribute__((ext_vector_type(4)));

#define EXPC 0.18033688011112042f   /* log2(e)/8 : exp(s/8) == exp2(s*EXPC) */

static __device__ __forceinline__ unsigned short f2bf(float f) {
  unsigned u = __float_as_uint(f);
  u += 0x7fffu + ((u >> 16) & 1u);
  return (unsigned short)(u >> 16);
}

static __device__ __forceinline__ int swz128(int row, int byteoff) {
  return row * 128 + (byteoff ^ ((row & 7) << 4));
}

// ---------------- LayerNorm -> bf16 ----------------
__global__ __launch_bounds__(256) void ln_kernel(
    const float* __restrict__ x, const float* __restrict__ gamma,
    const float* __restrict__ beta, unsigned short* __restrict__ xn)
{
  int row = blockIdx.x;
  int t = threadIdx.x;
  const float* xr = x + (size_t)row * D_;
  float v0 = xr[t], v1 = xr[t + 256];
  float s = v0 + v1, ss = v0 * v0 + v1 * v1;
  #pragma unroll
  for (int m = 1; m < 64; m <<= 1) {
    s  += __shfl_xor(s, m);
    ss += __shfl_xor(ss, m);
  }
  __shared__ float red[8];
  int wid = t >> 6;
  if ((t & 63) == 0) { red[wid] = s; red[wid + 4] = ss; }
  __syncthreads();
  s  = red[0] + red[1] + red[2] + red[3];
  ss = red[4] + red[5] + red[6] + red[7];
  float mu  = s * (1.0f / D_);
  float var = ss * (1.0f / D_) - mu * mu;
  float rstd = rsqrtf(var + 1e-5f);
  unsigned short* o = xn + (size_t)row * D_;
  o[t]       = f2bf((v0 - mu) * rstd * gamma[t]       + beta[t]);
  o[t + 256] = f2bf((v1 - mu) * rstd * gamma[t + 256] + beta[t + 256]);
}

// ---------------- weight casts ----------------
__global__ __launch_bounds__(256) void cast_w_kernel(
    const float* __restrict__ wq, const float* __restrict__ wk,
    const float* __restrict__ wv, const float* __restrict__ wo,
    unsigned short* __restrict__ wqkv, unsigned short* __restrict__ wob)
{
  int i = blockIdx.x * 256 + threadIdx.x;   // 262144 total
  wqkv[i]          = f2bf(wq[i]);
  wqkv[i + 262144] = f2bf(wk[i]);
  wqkv[i + 524288] = f2bf(wv[i]);
  wob[i]           = f2bf(wo[i]);
}

// ---------------- QKV GEMM: [8192,512] x [1536,512]^T ----------------
__global__ __launch_bounds__(256) void qkv_gemm(
    const unsigned short* __restrict__ xn,
    const unsigned short* __restrict__ wqkv,
    const float* __restrict__ bq, const float* __restrict__ bk,
    const float* __restrict__ bv,
    unsigned short* __restrict__ q, unsigned short* __restrict__ k,
    unsigned short* __restrict__ vT)
{
  __shared__ __align__(16) char As[128 * 128];
  __shared__ __align__(16) char Bs[128 * 128];
  const int m0 = blockIdx.x * 128;
  const int n0 = blockIdx.y * 128;
  const int t = threadIdx.x, wid = t >> 6, lane = t & 63;
  const int wr = (wid >> 1) * 64, wc = (wid & 1) * 64;
  const int cl = lane & 15, rg = lane >> 4;
  const f32x4 z4 = {0.f, 0.f, 0.f, 0.f};

  f32x4 acc[4][4];
  #pragma unroll
  for (int i = 0; i < 4; ++i)
    #pragma unroll
    for (int j = 0; j < 4; ++j) acc[i][j] = z4;

  for (int k0 = 0; k0 < 512; k0 += 64) {
    __syncthreads();
    #pragma unroll
    for (int i = 0; i < 4; ++i) {
      int c = t + 256 * i;
      int row = c >> 3, off = (c & 7) * 16;
      *(uint4*)(As + swz128(row, off)) =
          *(const uint4*)((const char*)(xn + (size_t)(m0 + row) * 512 + k0) + off);
      *(uint4*)(Bs + swz128(row, off)) =
          *(const uint4*)((const char*)(wqkv + (size_t)(n0 + row) * 512 + k0) + off);
    }
    __syncthreads();
    #pragma unroll
    for (int ks = 0; ks < 2; ++ks) {
      int koff = ks * 64 + rg * 16;
      bf16x8 af[4], bfr[4];
      #pragma unroll
      for (int i = 0; i < 4; ++i)
        af[i] = *(const bf16x8*)(As + swz128(wr + i * 16 + cl, koff));
      #pragma unroll
      for (int j = 0; j < 4; ++j)
        bfr[j] = *(const bf16x8*)(Bs + swz128(wc + j * 16 + cl, koff));
      #pragma unroll
      for (int i = 0; i < 4; ++i)
        #pragma unroll
        for (int j = 0; j < 4; ++j)
          acc[i][j] = __builtin_amdgcn_mfma_f32_16x16x32_bf16(af[i], bfr[j], acc[i][j], 0, 0, 0);
    }
  }

  #pragma unroll
  for (int j = 0; j < 4; ++j) {
    int n = n0 + wc + j * 16 + cl;
    int mat = n >> 9, nn = n & 511;
    int h = nn >> 6, dh = nn & 63;
    float bias = (mat == 0) ? bq[nn] : ((mat == 1) ? bk[nn] : bv[nn]);
    #pragma unroll
    for (int i = 0; i < 4; ++i) {
      #pragma unroll
      for (int r = 0; r < 4; ++r) {
        int mrow = m0 + wr + i * 16 + rg * 4 + r;
        int b = mrow >> 11, mm = mrow & 2047;
        unsigned short val = f2bf(acc[i][j][r] + bias);
        size_t bh = (size_t)(b * H_ + h);
        if (mat == 0)      q [(bh * M_ + mm) * DH_ + dh] = val;
        else if (mat == 1) k [(bh * M_ + mm) * DH_ + dh] = val;
        else               vT[(bh * DH_ + dh) * M_ + mm] = val;
      }
    }
  }
}

// ---------------- Attention v2: swapped-operand MFMA, no-max softmax ----------------
// grid: (32 m-blocks of 64 rows, 32 bh). block = 256 (4 waves x 16 Q-rows each).
__global__ __launch_bounds__(256) void attn_kernel(
    const unsigned short* __restrict__ q,
    const unsigned short* __restrict__ k,
    const unsigned short* __restrict__ vT,
    float* __restrict__ attn,
    unsigned short* __restrict__ ctx)
{
  __shared__ __align__(16) char Qs[64 * 128];
  __shared__ __align__(16) char Ks[64 * 128];
  __shared__ __align__(16) char Vs[64 * 128];
  __shared__ __align__(16) char Ps[64 * 128];

  const int bh = blockIdx.y;
  const int m0 = blockIdx.x * 64;
  const int t = threadIdx.x, wid = t >> 6, lane = t & 63;
  const int wr = wid * 16;                 // wave's 16 Q rows
  const int cl = lane & 15, rg = lane >> 4;
  const f32x4 z4 = {0.f, 0.f, 0.f, 0.f};
  const int diag_kt = m0 >> 6;             // the single K-tile containing the diagonal

  const unsigned short* qb = q  + (size_t)bh * M_ * DH_;
  const unsigned short* kb = k  + (size_t)bh * M_ * DH_;
  const unsigned short* vb = vT + (size_t)bh * DH_ * M_;
  float* ab = attn + (size_t)bh * M_ * M_;

  // stage Q tile (64 rows x 128B)
  #pragma unroll
  for (int i = 0; i < 2; ++i) {
    int c = t + 256 * i;
    int row = c >> 3, off = (c & 7) * 16;
    *(uint4*)(Qs + swz128(row, off)) =
        *(const uint4*)((const char*)qb + (size_t)(m0 + row) * 128 + off);
  }
  __syncthreads();

  // hoist Q fragments (B-operand: rows = m)
  bf16x8 qf[2];
  #pragma unroll
  for (int ks = 0; ks < 2; ++ks)
    qf[ks] = *(const bf16x8*)(Qs + swz128(wr + cl, ks * 64 + rg * 16));

  const int m_g = m0 + wr + cl;            // this lane's Q row (for all fragments)

  // ---- pass 1: row sums of exp2(s*EXPC), no max ----
  float psum = 0.f;
  for (int kt = 0; kt < 32; ++kt) {
    __syncthreads();
    #pragma unroll
    for (int i = 0; i < 2; ++i) {
      int c = t + 256 * i;
      int row = c >> 3, off = (c & 7) * 16;
      *(uint4*)(Ks + swz128(row, off)) =
          *(const uint4*)((const char*)kb + (size_t)(kt * 64 + row) * 128 + off);
    }
    __syncthreads();
    f32x4 s[4];
    #pragma unroll
    for (int j = 0; j < 4; ++j) s[j] = z4;
    #pragma unroll
    for (int ks = 0; ks < 2; ++ks) {
      #pragma unroll
      for (int j = 0; j < 4; ++j) {
        bf16x8 kf = *(const bf16x8*)(Ks + swz128(j * 16 + cl, ks * 64 + rg * 16));
        s[j] = __builtin_amdgcn_mfma_f32_16x16x32_bf16(kf, qf[ks], s[j], 0, 0, 0);
      }
    }
    if (kt == diag_kt) {
      #pragma unroll
      for (int j = 0; j < 4; ++j)
        #pragma unroll
        for (int r = 0; r < 4; ++r) {
          int n_g = kt * 64 + j * 16 + rg * 4 + r;
          float p = __builtin_amdgcn_exp2f(s[j][r] * EXPC);
          psum += (n_g == m_g) ? 0.f : p;
        }
    } else {
      #pragma unroll
      for (int j = 0; j < 4; ++j)
        #pragma unroll
        for (int r = 0; r < 4; ++r)
          psum += __builtin_amdgcn_exp2f(s[j][r] * EXPC);
    }
  }
  psum += __shfl_xor(psum, 16);
  psum += __shfl_xor(psum, 32);
  const float rinv = 1.0f / psum;

  // ---- pass 2: recompute S, write normalized attn (float4 NT), PV ----
  f32x4 oc[4];
  #pragma unroll
  for (int j = 0; j < 4; ++j) oc[j] = z4;

  for (int kt = 0; kt < 32; ++kt) {
    __syncthreads();
    #pragma unroll
    for (int i = 0; i < 2; ++i) {
      int c = t + 256 * i;
      int row = c >> 3, off = (c & 7) * 16;
      *(uint4*)(Ks + swz128(row, off)) =
          *(const uint4*)((const char*)kb + (size_t)(kt * 64 + row) * 128 + off);
      *(uint4*)(Vs + swz128(row, off)) =
          *(const uint4*)((const char*)vb + (size_t)row * (M_ * 2) + kt * 128 + off);
    }
    __syncthreads();
    f32x4 s[4];
    #pragma unroll
    for (int j = 0; j < 4; ++j) s[j] = z4;
    #pragma unroll
    for (int ks = 0; ks < 2; ++ks) {
      #pragma unroll
      for (int j = 0; j < 4; ++j) {
        bf16x8 kf = *(const bf16x8*)(Ks + swz128(j * 16 + cl, ks * 64 + rg * 16));
        s[j] = __builtin_amdgcn_mfma_f32_16x16x32_bf16(kf, qf[ks], s[j], 0, 0, 0);
      }
    }
    // emit P: each lane holds 4 consecutive n for its row m_g
    const bool dtile = (kt == diag_kt);
    float* arow = ab + (size_t)m_g * M_ + kt * 64 + rg * 4;
    #pragma unroll
    for (int j = 0; j < 4; ++j) {
      f32x4 pv;
      #pragma unroll
      for (int r = 0; r < 4; ++r) {
        int n_g = kt * 64 + j * 16 + rg * 4 + r;
        float p = __builtin_amdgcn_exp2f(s[j][r] * EXPC) * rinv;
        pv[r] = (dtile && n_g == m_g) ? 0.f : p;
      }
      __builtin_nontemporal_store(pv, (f32x4*)(arow + j * 16));
      u16x4 u;
      #pragma unroll
      for (int r = 0; r < 4; ++r) u[r] = f2bf(pv[r]);
      *(u16x4*)(Ps + swz128(wr + cl, j * 32 + rg * 8)) = u;
    }
    // PV: oc[jd] (rows = d, cols = m) += V_frag x P_frag
    #pragma unroll
    for (int ks = 0; ks < 2; ++ks) {
      bf16x8 pf = *(const bf16x8*)(Ps + swz128(wr + cl, ks * 64 + rg * 16));
      #pragma unroll
      for (int jd = 0; jd < 4; ++jd) {
        bf16x8 vf = *(const bf16x8*)(Vs + swz128(jd * 16 + cl, ks * 64 + rg * 16));
        oc[jd] = __builtin_amdgcn_mfma_f32_16x16x32_bf16(vf, pf, oc[jd], 0, 0, 0);
      }
    }
  }

  // ctx epilogue: lane holds 4 consecutive d for its row m_g -> 8B stores
  int b = bh >> 3, h = bh & 7;
  unsigned short* crow = ctx + ((size_t)b * M_ + m_g) * D_ + h * DH_ + rg * 4;
  #pragma unroll
  for (int jd = 0; jd < 4; ++jd) {
    u16x4 u;
    #pragma unroll
    for (int r = 0; r < 4; ++r) u[r] = f2bf(oc[jd][r]);
    *(u16x4*)(crow + jd * 16) = u;
  }
}

// ---------------- out = ctx @ wo^T + bo + x (swapped epilogue, float4) ----------------
__global__ __launch_bounds__(256) void out_gemm(
    const unsigned short* __restrict__ ctxb,
    const unsigned short* __restrict__ wob,
    const float* __restrict__ bo,
    const float* __restrict__ x,
    float* __restrict__ out)
{
  __shared__ __align__(16) char As[128 * 128];
  __shared__ __align__(16) char Bs[128 * 128];
  const int m0 = blockIdx.x * 128;
  const int n0 = blockIdx.y * 128;
  const int t = threadIdx.x, wid = t >> 6, lane = t & 63;
  const int wr = (wid >> 1) * 64, wc = (wid & 1) * 64;
  const int cl = lane & 15, rg = lane >> 4;
  const f32x4 z4 = {0.f, 0.f, 0.f, 0.f};

  f32x4 acc[4][4];   // [j: n frag][i: m frag], row=n, col=m
  #pragma unroll
  for (int j = 0; j < 4; ++j)
    #pragma unroll
    for (int i = 0; i < 4; ++i) acc[j][i] = z4;

  for (int k0 = 0; k0 < 512; k0 += 64) {
    __syncthreads();
    #pragma unroll
    for (int i = 0; i < 4; ++i) {
      int c = t + 256 * i;
      int row = c >> 3, off = (c & 7) * 16;
      *(uint4*)(As + swz128(row, off)) =
          *(const uint4*)((const char*)(ctxb + (size_t)(m0 + row) * 512 + k0) + off);
      *(uint4*)(Bs + swz128(row, off)) =
          *(const uint4*)((const char*)(wob + (size_t)(n0 + row) * 512 + k0) + off);
    }
    __syncthreads();
    #pragma unroll
    for (int ks = 0; ks < 2; ++ks) {
      int koff = ks * 64 + rg * 16;
      bf16x8 af[4], bfr[4];
      #pragma unroll
      for (int i = 0; i < 4; ++i)
        af[i] = *(const bf16x8*)(As + swz128(wr + i * 16 + cl, koff));
      #pragma unroll
      for (int j = 0; j < 4; ++j)
        bfr[j] = *(const bf16x8*)(Bs + swz128(wc + j * 16 + cl, koff));
      #pragma unroll
      for (int j = 0; j < 4; ++j)
        #pragma unroll
        for (int i = 0; i < 4; ++i)
          acc[j][i] = __builtin_amdgcn_mfma_f32_16x16x32_bf16(bfr[j], af[i], acc[j][i], 0, 0, 0);
    }
  }

  #pragma unroll
  for (int j = 0; j < 4; ++j) {
    int nb = n0 + wc + j * 16 + rg * 4;
    f32x4 bo4 = *(const f32x4*)(bo + nb);
    #pragma unroll
    for (int i = 0; i < 4; ++i) {
      int m = m0 + wr + i * 16 + cl;
      f32x4 x4 = *(const f32x4*)(x + (size_t)m * 512 + nb);
      f32x4 o;
      #pragma unroll
      for (int r = 0; r < 4; ++r) o[r] = acc[j][i][r] + bo4[r] + x4[r];
      *(f32x4*)(out + (size_t)m * 512 + nb) = o;
    }
  }
}

extern "C" void kernel_launch(void* const* d_in, const int* in_sizes, int n_in,
                              void* d_out, int out_size, void* d_ws, size_t ws_size,
                              hipStream_t stream) {
  const float* x     = (const float*)d_in[0];
  const float* wq    = (const float*)d_in[1];
  const float* bq    = (const float*)d_in[2];
  const float* wk    = (const float*)d_in[3];
  const float* bk    = (const float*)d_in[4];
  const float* wv    = (const float*)d_in[5];
  const float* bv    = (const float*)d_in[6];
  const float* wo    = (const float*)d_in[7];
  const float* bo    = (const float*)d_in[8];
  const float* gamma = (const float*)d_in[9];
  const float* beta  = (const float*)d_in[10];

  char* ws = (char*)d_ws;
  unsigned short* xn   = (unsigned short*)(ws);              //  8,388,608 B
  unsigned short* wqkv = (unsigned short*)(ws + 8388608);    //  1,572,864 B
  unsigned short* wob  = (unsigned short*)(ws + 9961472);    //    524,288 B
  unsigned short* qb   = (unsigned short*)(ws + 10485760);   //  8,388,608 B
  unsigned short* kb   = (unsigned short*)(ws + 18874368);   //  8,388,608 B
  unsigned short* vT   = (unsigned short*)(ws + 27262976);   //  8,388,608 B
  unsigned short* ctx  = (unsigned short*)(ws + 35651584);   //  8,388,608 B

  float* out  = (float*)d_out;
  float* attn = (float*)d_out + 4194304;

  ln_kernel<<<8192, 256, 0, stream>>>(x, gamma, beta, xn);
  cast_w_kernel<<<1024, 256, 0, stream>>>(wq, wk, wv, wo, wqkv, wob);
  qkv_gemm<<<dim3(64, 12), 256, 0, stream>>>(xn, wqkv, bq, bk, bv, qb, kb, vT);
  attn_kernel<<<dim3(32, 32), 256, 0, stream>>>(qb, kb, vT, attn, ctx);
  out_gemm<<<dim3(64, 4), 256, 0, stream>>>(ctx, wob, bo, x, out);
}